// Round 4
// baseline (147.426 us; speedup 1.0000x reference)
//
#include <hip/hip_runtime.h>

// Problem constants: N=B*T=65536, D=256, K=1024
#define NTOT 65536
#define DDIM 256
#define KCB  1024
#define ND   16777216   // NTOT * DDIM
#define NBLK 512        // 512 blocks x 4 independent waves; wave owns 32 rows x 1024 cols

typedef __attribute__((ext_vector_type(4))) float f32x4;
typedef __attribute__((ext_vector_type(4))) int   i32x4;
typedef __attribute__((ext_vector_type(2))) long long i64x2;

__device__ static inline unsigned umax32(unsigned a, unsigned b) { return a > b ? a : b; }

// ---- fp32 -> fp8 e4m3fn (OCP), 4-at-a-time pack into an int (byte i = x_i) --
#if !__has_builtin(__builtin_amdgcn_cvt_pk_fp8_f32)
__device__ static inline unsigned f32_to_e4m3_1(float f) {
    unsigned u = __float_as_uint(f);
    unsigned s = (u >> 24) & 0x80u;
    unsigned a = u & 0x7fffffffu;
    float x = __uint_as_float(a);
    if (x >= 448.f) return s | 0x7Eu;
    if (x < 0.015625f) {                    // subnormal: multiples of 2^-9
        int m = (int)__builtin_rintf(x * 512.f);   // RNE, 0..8
        return s | (unsigned)m;             // m==8 -> 0x08 == 2^-6 normal, correct
    }
    unsigned r = (a + 0x7FFFFu + ((a >> 20) & 1u)) >> 20;   // RNE to 3 mantissa bits
    int E = (int)(r >> 3) - 127;
    unsigned code = ((unsigned)(E + 7) << 3) | (r & 7u);
    if (code >= 0x7Fu) code = 0x7Eu;
    return s | code;
}
#endif

__device__ static inline int pk4_fp8(float x0, float x1, float x2, float x3) {
#if __has_builtin(__builtin_amdgcn_cvt_pk_fp8_f32)
    int w = __builtin_amdgcn_cvt_pk_fp8_f32(x0, x1, 0, false);   // bytes 0,1
    w = __builtin_amdgcn_cvt_pk_fp8_f32(x2, x3, w, true);        // bytes 2,3
    return w;
#else
    return (int)(f32_to_e4m3_1(x0) | (f32_to_e4m3_1(x1) << 8) |
                 (f32_to_e4m3_1(x2) << 16) | (f32_to_e4m3_1(x3) << 24));
#endif
}

// ---------------- Prep: codebook -> fp8(x512) fragments + biased esq ---------
// Fragment layout UNCHANGED. esq now stores 64 - 256*||e||^2 (pre-biased for
// direct use as the MFMA C-init in the main kernel).
__global__ __launch_bounds__(256) void vq_prep_kernel(const float* __restrict__ cb,
                                                      char* __restrict__ cbf,
                                                      float* __restrict__ esq_scaled,
                                                      float* __restrict__ loss_out) {
    int gid = blockIdx.x * 256 + threadIdx.x;   // 0..32767
    int c = gid >> 5;
    int j8 = gid & 31;
    const float* p = cb + (size_t)c * DDIM + j8 * 8;
    f32x4 x = *(const f32x4*)p;
    f32x4 y = *(const f32x4*)(p + 4);
    float ss = x[0]*x[0] + x[1]*x[1] + x[2]*x[2] + x[3]*x[3]
             + y[0]*y[0] + y[1]*y[1] + y[2]*y[2] + y[3]*y[3];
    #pragma unroll
    for (int m = 16; m; m >>= 1) ss += __shfl_xor(ss, m);   // reduce the 32 lanes of code c
    if (j8 == 0) esq_scaled[c] = 64.0f - 256.f * ss;        // pre-biased, pre-negated
    int w0 = pk4_fp8(512.f * x[0], 512.f * x[1], 512.f * x[2], 512.f * x[3]);
    int w1 = pk4_fp8(512.f * y[0], 512.f * y[1], 512.f * y[2], 512.f * y[3]);
    int ks = j8 >> 2, qq = j8 & 3;
    int cc = c >> 4, kp = ks >> 1, h = ks & 1;
    int lane2 = qq * 16 + (c & 15);
    size_t addr = ((size_t)(cc * 4 + kp) * 64 + lane2) * 16 + h * 8;
    *(long long*)(cbf + addr) = (long long)(unsigned)w0 | ((long long)w1 << 32);
    if (gid == 0) loss_out[0] = 0.f;
}

// ---------------- Main: zero-barrier, zero-LDS wave-independent kernel -------
// 512 blocks x 256 thr = 2048 fully independent waves. Wave owns 32 rows x all
// 1024 cols: no cross-wave argmin -> no LDS, no __syncthreads anywhere. Waves
// drift freely across phases, so MFMA / VALU / L2 / HBM pipes stay mixed
// (lockstep phase serialization was the r1-r3 limiter). B-fragments stream
// from the L2-resident 256 KB cbf (ping-pong, 1 chunk ahead); esq prefetched
// one chunk ahead the same way. Argmin via packed keys (acc init = 64-256||e||^2
// => final acc > 0; key = (as_uint & ~1023) | (1023-col)); exact lowest-index
// tie-break. Loss analytic from the winning key. Gather straight from regs.
__global__ __launch_bounds__(256, 2) void vq_main_kernel(const float* __restrict__ z,
                                                         const float* __restrict__ cb,
                                                         const char* __restrict__ cbf,
                                                         const float* __restrict__ esq_scaled,
                                                         float* __restrict__ out) {
    const int tid  = threadIdx.x;
    const int w    = tid >> 6;
    const int lane = tid & 63;
    const int q    = lane >> 4;
    const int ln   = lane & 15;
    const int base = (blockIdx.x * 4 + w) * 32;   // rows base..base+31

    // B chunk-0 prefetch (L2-resident after first touch) + esq chunk-0
    const char* bbase = cbf + (size_t)lane * 16;
    i32x4 B0[4], B1[4];
    #pragma unroll
    for (int kp = 0; kp < 4; ++kp)
        B0[kp] = *(const i32x4*)(bbase + kp * 1024);
    float e_cur = esq_scaled[ln];

    // ---- A frags direct global->reg pack + exact fp32 ||z_row||^2 ---------
    // A layout: lane(q,ln) row = base+rf*16+ln, k = ks*32 + q*8 + j.
    long long a[2][8];
    float zq[2];
    #pragma unroll
    for (int rf = 0; rf < 2; ++rf) {
        const float* ap = z + (size_t)(base + rf * 16 + ln) * DDIM + q * 8;
        float sq = 0.f;
        #pragma unroll
        for (int ks = 0; ks < 8; ++ks) {
            f32x4 x = *(const f32x4*)(ap + ks * 32);
            f32x4 y = *(const f32x4*)(ap + ks * 32 + 4);
            sq += x[0]*x[0] + x[1]*x[1] + x[2]*x[2] + x[3]*x[3]
                + y[0]*y[0] + y[1]*y[1] + y[2]*y[2] + y[3]*y[3];
            int w0 = pk4_fp8(x[0], x[1], x[2], x[3]);
            int w1 = pk4_fp8(y[0], y[1], y[2], y[3]);
            a[rf][ks] = (long long)(unsigned)w0 | ((long long)w1 << 32);
        }
        sq += __shfl_xor(sq, 16);
        sq += __shfl_xor(sq, 32);   // full row sum (over the 4 q-slices) in every lane
        zq[rf] = sq;
    }

    unsigned best[8];
    #pragma unroll
    for (int i = 0; i < 8; ++i) best[i] = 0u;
    const int colinv0 = 1023 - ln;

    // ---- K-loop: 64 chunks of 16 cols, ping-pong prefetch, no barriers -----
    // 4 independent MFMA chains (depth 4) to cover dep latency at low TLP.
#define VQ_STEP(Bc_, Bn_, C_, CN_)                                             \
    {                                                                          \
        _Pragma("unroll")                                                      \
        for (int kp = 0; kp < 4; ++kp)                                         \
            Bn_[kp] = *(const i32x4*)(bbase + (size_t)((CN_) * 4 + kp) * 1024);\
        float e_next = esq_scaled[(CN_) * 16 + ln];                            \
        f32x4 aa0 = {e_cur, e_cur, e_cur, e_cur};                              \
        f32x4 aa1 = aa0;                                                       \
        f32x4 ab0 = {0.f, 0.f, 0.f, 0.f};                                      \
        f32x4 ab1 = ab0;                                                       \
        __builtin_amdgcn_s_setprio(1);                                         \
        _Pragma("unroll")                                                      \
        for (int kp = 0; kp < 2; ++kp) {                                       \
            i64x2 pr = __builtin_bit_cast(i64x2, Bc_[kp]);                     \
            aa0 = __builtin_amdgcn_mfma_f32_16x16x32_fp8_fp8(a[0][2*kp],   pr[0], aa0, 0, 0, 0); \
            aa1 = __builtin_amdgcn_mfma_f32_16x16x32_fp8_fp8(a[1][2*kp],   pr[0], aa1, 0, 0, 0); \
            aa0 = __builtin_amdgcn_mfma_f32_16x16x32_fp8_fp8(a[0][2*kp+1], pr[1], aa0, 0, 0, 0); \
            aa1 = __builtin_amdgcn_mfma_f32_16x16x32_fp8_fp8(a[1][2*kp+1], pr[1], aa1, 0, 0, 0); \
        }                                                                      \
        _Pragma("unroll")                                                      \
        for (int kp = 2; kp < 4; ++kp) {                                       \
            i64x2 pr = __builtin_bit_cast(i64x2, Bc_[kp]);                     \
            ab0 = __builtin_amdgcn_mfma_f32_16x16x32_fp8_fp8(a[0][2*kp],   pr[0], ab0, 0, 0, 0); \
            ab1 = __builtin_amdgcn_mfma_f32_16x16x32_fp8_fp8(a[1][2*kp],   pr[0], ab1, 0, 0, 0); \
            ab0 = __builtin_amdgcn_mfma_f32_16x16x32_fp8_fp8(a[0][2*kp+1], pr[1], ab0, 0, 0, 0); \
            ab1 = __builtin_amdgcn_mfma_f32_16x16x32_fp8_fp8(a[1][2*kp+1], pr[1], ab1, 0, 0, 0); \
        }                                                                      \
        __builtin_amdgcn_s_setprio(0);                                         \
        f32x4 s0 = aa0 + ab0;                                                  \
        f32x4 s1 = aa1 + ab1;                                                  \
        const unsigned ci = (unsigned)(colinv0 - (C_) * 16);                   \
        _Pragma("unroll")                                                      \
        for (int i = 0; i < 4; ++i) {                                          \
            best[i]     = umax32(best[i],     (__float_as_uint(s0[i]) & 0xFFFFFC00u) | ci); \
            best[4 + i] = umax32(best[4 + i], (__float_as_uint(s1[i]) & 0xFFFFFC00u) | ci); \
        }                                                                      \
        e_cur = e_next;                                                        \
    }

    for (int c = 0; c < 64; c += 2) {
        VQ_STEP(B0, B1, c, c + 1);
        VQ_STEP(B1, B0, c + 1, (c + 2) & 63);   // wraps to 0: harmless re-read
    }
#undef VQ_STEP

    // ---- reduce over the 16 ln-lanes of each q-group (integer max only) ----
    // After this, every lane of q-group holds winners for rows base+rf*16+q*4+i.
    #pragma unroll
    for (int m = 1; m < 16; m <<= 1)
        #pragma unroll
        for (int i = 0; i < 8; ++i)
            best[i] = umax32(best[i], (unsigned)__shfl_xor((int)best[i], m));

    // ---- loss: lane (q, ln=q*4+i) has zq for exactly the winner rows -------
    float lcl = 0.f;
    if ((ln >> 2) == q) {
        const int i = ln & 3;
        #pragma unroll
        for (int rf = 0; rf < 2; ++rf) {
            unsigned u = best[rf * 4 + i];
            // midpoint-reconstruct truncated score: s+64
            float sval = __uint_as_float((u & 0xFFFFFC00u) | 0x200u) - 64.0f;
            lcl += zq[rf] - sval * 0.00390625f;   // ||z-e*||^2 = ||z||^2 - s/256
        }
    }
    #pragma unroll
    for (int off = 32; off; off >>= 1) lcl += __shfl_xor(lcl, off);
    if (lane == 0) atomicAdd(out + ND, lcl * (1.0f / (float)ND));

    // ---- gather + NT store straight from registers -------------------------
    #pragma unroll
    for (int rf = 0; rf < 2; ++rf)
        #pragma unroll
        for (int i = 0; i < 4; ++i) {
            const int row = base + rf * 16 + q * 4 + i;
            const int k = 1023 - (int)(best[rf * 4 + i] & 1023u);
            const float* src = cb + (size_t)k * DDIM + ln * 4;
            float* dst = out + (size_t)row * DDIM + ln * 4;
            #pragma unroll
            for (int j = 0; j < 4; ++j) {
                f32x4 v = *(const f32x4*)(src + j * 64);
                __builtin_nontemporal_store(v, (f32x4*)(dst + j * 64));
            }
        }
}

extern "C" void kernel_launch(void* const* d_in, const int* in_sizes, int n_in,
                              void* d_out, int out_size, void* d_ws, size_t ws_size,
                              hipStream_t stream) {
    const float* z  = (const float*)d_in[0];   // z_e, 65536 x 256 fp32
    const float* cb = (const float*)d_in[1];   // codebook, 1024 x 256 fp32
    float* out = (float*)d_out;                // z_q (16777216) ++ loss (1)

    float* esq_scaled = (float*)d_ws;                    // 4 KB
    char*  cb_frag    = (char*)d_ws + 4096;              // 256 KB fp8 fragments

    vq_prep_kernel<<<128, 256, 0, stream>>>(cb, cb_frag, esq_scaled, out + ND);
    vq_main_kernel<<<NBLK, 256, 0, stream>>>(z, cb, cb_frag, esq_scaled, out);
}

// Round 5
// 135.212 us; speedup vs baseline: 1.0903x; 1.0903x over previous
//
#include <hip/hip_runtime.h>

// Problem constants: N=B*T=65536, D=256, K=1024
#define NTOT 65536
#define DDIM 256
#define KCB  1024
#define ND   16777216   // NTOT * DDIM

typedef __attribute__((ext_vector_type(4))) float f32x4;
typedef __attribute__((ext_vector_type(4))) int   i32x4;
typedef __attribute__((ext_vector_type(8))) int   i32x8;
typedef __attribute__((ext_vector_type(4))) unsigned u32x4;

__device__ static inline unsigned umax32(unsigned a, unsigned b) { return a > b ? a : b; }

// ---- fp32 -> fp8 e4m3fn (OCP), 4-at-a-time pack into an int (byte i = x_i) --
#if !__has_builtin(__builtin_amdgcn_cvt_pk_fp8_f32)
__device__ static inline unsigned f32_to_e4m3_1(float f) {
    unsigned u = __float_as_uint(f);
    unsigned s = (u >> 24) & 0x80u;
    unsigned a = u & 0x7fffffffu;
    float x = __uint_as_float(a);
    if (x >= 448.f) return s | 0x7Eu;
    if (x < 0.015625f) {                    // subnormal: multiples of 2^-9
        int m = (int)__builtin_rintf(x * 512.f);   // RNE, 0..8
        return s | (unsigned)m;             // m==8 -> 0x08 == 2^-6 normal, correct
    }
    unsigned r = (a + 0x7FFFFu + ((a >> 20) & 1u)) >> 20;   // RNE to 3 mantissa bits
    int E = (int)(r >> 3) - 127;
    unsigned code = ((unsigned)(E + 7) << 3) | (r & 7u);
    if (code >= 0x7Fu) code = 0x7Eu;
    return s | code;
}
#endif

__device__ static inline int pk4_fp8(float x0, float x1, float x2, float x3) {
#if __has_builtin(__builtin_amdgcn_cvt_pk_fp8_f32)
    int w = __builtin_amdgcn_cvt_pk_fp8_f32(x0, x1, 0, false);   // bytes 0,1
    w = __builtin_amdgcn_cvt_pk_fp8_f32(x2, x3, w, true);        // bytes 2,3
    return w;
#else
    return (int)(f32_to_e4m3_1(x0) | (f32_to_e4m3_1(x1) << 8) |
                 (f32_to_e4m3_1(x2) << 16) | (f32_to_e4m3_1(x3) << 24));
#endif
}

// ---------------- Prep: codebook -> fp8(x512) MX-fragments + 256*||e||^2 -----
// Fragment layout for mfma_scale_f32_16x16x128_f8f6f4: lane l of a B-frag
// holds col = l&15, k = kf*128 + (l>>4)*32 + j (j=0..31), as two 16-B granules
// h (bytes j<16 / j>=16). Byte addr:
//   ((cc*2 + kf)*2 + h)*1024 + ((q)*16 + (c&15))*16 + (k&15)
// where cc = c>>4 (16-col chunk), q = (k>>5)&3.
__global__ __launch_bounds__(256) void vq_prep_kernel(const float* __restrict__ cb,
                                                      char* __restrict__ cbf,
                                                      float* __restrict__ esq_scaled,
                                                      float* __restrict__ loss_out) {
    int gid = blockIdx.x * 256 + threadIdx.x;   // 0..32767
    int c = gid >> 5;
    int j8 = gid & 31;                          // owns k = j8*8 .. j8*8+7
    const float* p = cb + (size_t)c * DDIM + j8 * 8;
    f32x4 x = *(const f32x4*)p;
    f32x4 y = *(const f32x4*)(p + 4);
    float ss = x[0]*x[0] + x[1]*x[1] + x[2]*x[2] + x[3]*x[3]
             + y[0]*y[0] + y[1]*y[1] + y[2]*y[2] + y[3]*y[3];
    #pragma unroll
    for (int m = 16; m; m >>= 1) ss += __shfl_xor(ss, m);   // reduce the 32 lanes of code c
    if (j8 == 0) esq_scaled[c] = 256.f * ss;                // 512 * 0.5 * ||e||^2
    int w0 = pk4_fp8(512.f * x[0], 512.f * x[1], 512.f * x[2], 512.f * x[3]);
    int w1 = pk4_fp8(512.f * y[0], 512.f * y[1], 512.f * y[2], 512.f * y[3]);
    // k = j8*8: kf = j8>>4, q = (j8>>2)&3, h = (j8>>1)&1, byte = (j8&1)*8
    int cc = c >> 4, kf = j8 >> 4, q = (j8 >> 2) & 3, h = (j8 >> 1) & 1;
    size_t addr = (size_t)(((cc * 2 + kf) * 2 + h) * 1024)
                + (size_t)(q * 16 + (c & 15)) * 16 + (j8 & 1) * 8;
    *(long long*)(cbf + addr) = (long long)(unsigned)w0 | ((long long)w1 << 32);
    if (gid == 0) loss_out[0] = 0.f;
}

// ---------------- Main: r1 structure + MX-scaled K=128 MFMA (2x rate) --------
// 1024 blocks x 256 thr (4 waves, rg x cg: wave cg owns 64 rows x 256 cols).
// Identical schedule to the proven 50us kernel; only the MFMA family changed:
// 8x mfma_scale_f32_16x16x128_f8f6f4 per 16-col chunk (scale=E8M0 127 = x1.0,
// bit-exact vs non-scaled fp8) instead of 32x 16x16x32 -> MFMA pipe time
// halves (4.66 PF MX rate vs 2.1 PF). Argmin via packed keys:
// acc init = 64-256||e||^2 => final acc = s+64 > 0;
// key = (as_uint & ~1023) | (1023-col); exact lowest-index tie-break.
__global__ __launch_bounds__(256, 3) void vq_main_kernel(const float* __restrict__ z,
                                                         const float* __restrict__ cb,
                                                         const char* __restrict__ cbf,
                                                         const float* __restrict__ esq_scaled,
                                                         float* __restrict__ out) {
    __shared__ i32x4 A4[1024];          // 16 KB: granule ((rf*2+kf)*2+h)*64 + lane
    __shared__ float esq_s[KCB];        // 4 KB: 64 - 256*||e||^2
    __shared__ float zsq_s[64];
    __shared__ unsigned ur_s[256];      // [cg][row] packed keys
    __shared__ int idx_s[64];

    const int tid  = threadIdx.x;
    const int cg   = tid >> 6;          // wave id = column group (cols cg*256..)
    const int lane = tid & 63;
    const int q    = lane >> 4;
    const int ln   = lane & 15;
    // pack mapping: thread (r, t) owns row r, cols t*64..t*64+63
    const int r = tid >> 2, t = tid & 3;
    const int mm = r & 15;
    const int rf_own = r >> 4;
    const int b0 = blockIdx.x * 64;

    #pragma unroll
    for (int i = 0; i < 4; ++i) {
        int ix = tid + i * 256;
        esq_s[ix] = 64.0f - esq_scaled[ix];   // bias +64 folded in, negated
    }

    // early B prefetch for chunk 0 (L2-resident after first touch)
    // chunk byte stride within cg region: 4096 (2 kf x 2 h x 1024)
    const char* bbase = cbf + (size_t)cg * 65536 + lane * 16;
    i32x4 Bc[4], Bn[4];                 // [kf*2 + h]
    #pragma unroll
    for (int j = 0; j < 4; ++j)
        Bc[j] = *(const i32x4*)(bbase + j * 1024);

    // ---- cooperative A load/pack: thread (r, t) owns 64 floats -------------
    {
        const float* zp = z + (size_t)(b0 + r) * DDIM + t * 64;
        f32x4 v[16];
        #pragma unroll
        for (int i = 0; i < 16; ++i) v[i] = *(const f32x4*)(zp + i * 4);
        float sq = 0.f;
        #pragma unroll
        for (int s = 0; s < 2; ++s) {           // k-32-block kb = 2t+s
            const int kb = 2 * t + s;
            const int kf = kb >> 2, qq = kb & 3;
            int w[8];
            #pragma unroll
            for (int j = 0; j < 8; ++j) {
                f32x4 x = v[s * 8 + j];
                sq += x[0]*x[0] + x[1]*x[1] + x[2]*x[2] + x[3]*x[3];
                w[j] = pk4_fp8(x[0], x[1], x[2], x[3]);
            }
            const int g = ((rf_own * 2 + kf) * 2) * 64 + qq * 16 + mm;
            A4[g]      = (i32x4){w[0], w[1], w[2], w[3]};   // h=0
            A4[g + 64] = (i32x4){w[4], w[5], w[6], w[7]};   // h=1
        }
        sq += __shfl_xor(sq, 1);
        sq += __shfl_xor(sq, 2);               // row sum over the 4 t-lanes
        if (t == 0) zsq_s[r] = sq;
    }
    __syncthreads();

    // ---- A frags to regs: lane-contiguous ds_read_b128 (conflict-free) ----
    i32x8 av[4][2];
    #pragma unroll
    for (int rf = 0; rf < 4; ++rf)
        #pragma unroll
        for (int kf = 0; kf < 2; ++kf) {
            i32x4* ph = (i32x4*)&av[rf][kf];
            ph[0] = A4[((rf * 2 + kf) * 2 + 0) * 64 + lane];
            ph[1] = A4[((rf * 2 + kf) * 2 + 1) * 64 + lane];
        }

    unsigned best[16];
    #pragma unroll
    for (int i = 0; i < 16; ++i) best[i] = 0u;
    const float* ep = esq_s + cg * 256 + ln;
    const int colinv0 = 1023 - cg * 256 - ln;

    // ---- K-loop: 16 chunks of 16 cols, ping-pong prefetch, no barriers -----
#define VQ_STEP(Bc_, Bn_, C_, CN_)                                             \
    {                                                                          \
        _Pragma("unroll")                                                      \
        for (int j = 0; j < 4; ++j)                                            \
            Bn_[j] = *(const i32x4*)(bbase + (size_t)(CN_) * 4096 + j * 1024); \
        const float e4 = ep[(C_) * 16];                                        \
        f32x4 ac0 = {e4, e4, e4, e4};                                          \
        f32x4 ac1 = ac0, ac2 = ac0, ac3 = ac0;                                 \
        i32x8 bv0, bv1;                                                        \
        ((i32x4*)&bv0)[0] = Bc_[0]; ((i32x4*)&bv0)[1] = Bc_[1];                \
        ((i32x4*)&bv1)[0] = Bc_[2]; ((i32x4*)&bv1)[1] = Bc_[3];                \
        __builtin_amdgcn_s_setprio(1);                                         \
        ac0 = __builtin_amdgcn_mfma_scale_f32_16x16x128_f8f6f4(av[0][0], bv0, ac0, 0, 0, 0, 0x7F7F7F7F, 0, 0x7F7F7F7F); \
        ac1 = __builtin_amdgcn_mfma_scale_f32_16x16x128_f8f6f4(av[1][0], bv0, ac1, 0, 0, 0, 0x7F7F7F7F, 0, 0x7F7F7F7F); \
        ac2 = __builtin_amdgcn_mfma_scale_f32_16x16x128_f8f6f4(av[2][0], bv0, ac2, 0, 0, 0, 0x7F7F7F7F, 0, 0x7F7F7F7F); \
        ac3 = __builtin_amdgcn_mfma_scale_f32_16x16x128_f8f6f4(av[3][0], bv0, ac3, 0, 0, 0, 0x7F7F7F7F, 0, 0x7F7F7F7F); \
        ac0 = __builtin_amdgcn_mfma_scale_f32_16x16x128_f8f6f4(av[0][1], bv1, ac0, 0, 0, 0, 0x7F7F7F7F, 0, 0x7F7F7F7F); \
        ac1 = __builtin_amdgcn_mfma_scale_f32_16x16x128_f8f6f4(av[1][1], bv1, ac1, 0, 0, 0, 0x7F7F7F7F, 0, 0x7F7F7F7F); \
        ac2 = __builtin_amdgcn_mfma_scale_f32_16x16x128_f8f6f4(av[2][1], bv1, ac2, 0, 0, 0, 0x7F7F7F7F, 0, 0x7F7F7F7F); \
        ac3 = __builtin_amdgcn_mfma_scale_f32_16x16x128_f8f6f4(av[3][1], bv1, ac3, 0, 0, 0, 0x7F7F7F7F, 0, 0x7F7F7F7F); \
        __builtin_amdgcn_s_setprio(0);                                         \
        const unsigned ci = (unsigned)(colinv0 - (C_) * 16);                   \
        _Pragma("unroll")                                                      \
        for (int i = 0; i < 4; ++i) {                                          \
            best[i]      = umax32(best[i],      (__float_as_uint(ac0[i]) & 0xFFFFFC00u) | ci); \
            best[4 + i]  = umax32(best[4 + i],  (__float_as_uint(ac1[i]) & 0xFFFFFC00u) | ci); \
            best[8 + i]  = umax32(best[8 + i],  (__float_as_uint(ac2[i]) & 0xFFFFFC00u) | ci); \
            best[12 + i] = umax32(best[12 + i], (__float_as_uint(ac3[i]) & 0xFFFFFC00u) | ci); \
        }                                                                      \
    }

    for (int c = 0; c < 16; c += 2) {
        VQ_STEP(Bc, Bn, c, c + 1);
        VQ_STEP(Bn, Bc, c + 1, (c + 2) & 15);   // wraps to 0: harmless re-read
    }
#undef VQ_STEP

    // ---- reduce over the 16 ln-lanes of each q-group (integer max only) ----
    #pragma unroll
    for (int m = 1; m < 16; m <<= 1)
        #pragma unroll
        for (int i = 0; i < 16; ++i)
            best[i] = umax32(best[i], (unsigned)__shfl_xor((int)best[i], m));

    if (ln == 0) {
        #pragma unroll
        for (int rf = 0; rf < 4; ++rf) {
            u32x4 v = {best[rf * 4 + 0], best[rf * 4 + 1],
                       best[rf * 4 + 2], best[rf * 4 + 3]};
            *(u32x4*)(ur_s + cg * 64 + rf * 16 + q * 4) = v;   // rows rf*16+q*4+i
        }
    }
    __syncthreads();

    if (tid < 64) {
        unsigned u = umax32(umax32(ur_s[tid], ur_s[64 + tid]),
                            umax32(ur_s[128 + tid], ur_s[192 + tid]));
        int k = 1023 - (int)(u & 1023u);
        // midpoint-reconstruct the truncated score: s+64
        float sval = __uint_as_float((u & 0xFFFFFC00u) | 0x200u) - 64.0f;
        idx_s[tid] = k;
        // row loss: ||z-e*||^2 = ||z||^2 - s/256
        float lsum = zsq_s[tid] - sval * 0.00390625f;
        #pragma unroll
        for (int off = 32; off; off >>= 1) lsum += __shfl_down(lsum, off);
        if (tid == 0) atomicAdd(out + ND, lsum * (1.0f / (float)ND));
    }
    __syncthreads();

    // ---- epilogue: float4 gather + non-temporal store ----------------------
    #pragma unroll
    for (int i = 0; i < 16; ++i) {
        int item = tid + i * 256;
        int row = item >> 6, c4 = item & 63;
        int k = idx_s[row];
        f32x4 v = *(const f32x4*)(cb + (size_t)k * DDIM + c4 * 4);
        __builtin_nontemporal_store(v, (f32x4*)(out + (size_t)(b0 + row) * DDIM + c4 * 4));
    }
}

extern "C" void kernel_launch(void* const* d_in, const int* in_sizes, int n_in,
                              void* d_out, int out_size, void* d_ws, size_t ws_size,
                              hipStream_t stream) {
    const float* z  = (const float*)d_in[0];   // z_e, 65536 x 256 fp32
    const float* cb = (const float*)d_in[1];   // codebook, 1024 x 256 fp32
    float* out = (float*)d_out;                // z_q (16777216) ++ loss (1)

    float* esq_scaled = (float*)d_ws;                    // 4 KB
    char*  cb_frag    = (char*)d_ws + 4096;              // 256 KB fp8 MX fragments

    vq_prep_kernel<<<128, 256, 0, stream>>>(cb, cb_frag, esq_scaled, out + ND);
    vq_main_kernel<<<NTOT / 64, 256, 0, stream>>>(z, cb, cb_frag, esq_scaled, out);
}